// Round 1
// baseline (109.047 us; speedup 1.0000x reference)
//
#include <hip/hip_runtime.h>

// Blockwise int8 dequant: out[i] = code[w[i] & 255] * absmax[i / 4096]
// w: [64Mi] int32 codes in [0,256); absmax: [16384] f32; code: [256] f32.
// Memory-bound: 256 MB read + 256 MB write -> target ~81 us @ 6.3 TB/s.

#define DEQ_BLOCKSIZE 4096

__global__ __launch_bounds__(256) void dequant_blockwise_kernel(
    const int* __restrict__ w,
    const float* __restrict__ absmax,
    const float* __restrict__ code,
    float* __restrict__ out,
    long n4)  // number of int4/float4 vectors
{
    __shared__ float lcode[256];
    // blockDim.x == 256: every thread loads one codebook entry.
    lcode[threadIdx.x] = code[threadIdx.x];
    __syncthreads();

    const long stride = (long)gridDim.x * blockDim.x;
    for (long i = (long)blockIdx.x * blockDim.x + threadIdx.x; i < n4; i += stride) {
        int4 wv = reinterpret_cast<const int4*>(w)[i];
        // 4096 elems/block = 1024 vec4 per absmax block; all 4 lanes share it.
        float am = absmax[i >> 10];
        float4 o;
        o.x = lcode[wv.x & 255] * am;
        o.y = lcode[wv.y & 255] * am;
        o.z = lcode[wv.z & 255] * am;
        o.w = lcode[wv.w & 255] * am;
        reinterpret_cast<float4*>(out)[i] = o;
    }
}

extern "C" void kernel_launch(void* const* d_in, const int* in_sizes, int n_in,
                              void* d_out, int out_size, void* d_ws, size_t ws_size,
                              hipStream_t stream) {
    const int*   w      = (const int*)d_in[0];
    const float* absmax = (const float*)d_in[1];
    const float* code   = (const float*)d_in[2];
    float*       out    = (float*)d_out;

    const long n  = (long)in_sizes[0];   // 8192*8192 = 67,108,864
    const long n4 = n >> 2;              // divisible by 4 (BLOCKSIZE=4096)

    // Memory-bound: cap grid at ~8 blocks/CU and grid-stride the rest.
    const int threads = 256;
    const int blocks  = 2048;
    dequant_blockwise_kernel<<<blocks, threads, 0, stream>>>(w, absmax, code, out, n4);
}